// Round 12
// baseline (1372.998 us; speedup 1.0000x reference)
//
#include <hip/hip_runtime.h>
#include <hip/hip_bf16.h>
#include <math.h>

#define NTH 256

typedef __bf16 bf16x8 __attribute__((ext_vector_type(8)));
typedef float  f32x4  __attribute__((ext_vector_type(4)));
typedef unsigned short ushort;
typedef ushort u16x8 __attribute__((ext_vector_type(8)));

__device__ __forceinline__ ushort f2bf(float x){
    union { float f; unsigned int u; } v; v.f = x;
    unsigned int r = v.u + 0x7fffu + ((v.u >> 16) & 1u);
    return (ushort)(r >> 16);
}
__device__ __forceinline__ float bf2f(ushort h){
    union { unsigned int u; float f; } v; v.u = ((unsigned int)h) << 16;
    return v.f;
}

// ============================ prep kernels ============================
__global__ void prep_combined_bf(const float* __restrict__ Wq, const float* __restrict__ Wk,
                                 const float* __restrict__ Wv, const float* __restrict__ in_w,
                                 ushort* __restrict__ dh)
{
    int o = blockIdx.x*NTH + threadIdx.x;
    if (o >= 76800) return;
    int c = o/160, j = o - c*160;
    const float* Wsel = (c<160) ? Wq : (c<320) ? Wk : Wv;
    const float* wrow = Wsel + j*160;
    const float* irow = in_w + c*160;
    float s = 0.f;
    for (int k=0;k<160;k++) s = fmaf(wrow[k], irow[k], s);
    dh[o] = f2bf(s);
}

__global__ void prep_H_split(const float* __restrict__ f_in_w, const float* __restrict__ out_w,
                             ushort* __restrict__ dh, float* __restrict__ tmp)
{
    int o = blockIdx.x*NTH + threadIdx.x;
    if (o >= 76800) return;
    int n = o/160, k = o - n*160;
    float s = 0.f;
    for (int c=0;c<160;c++) s = fmaf(f_in_w[n*160+c], out_w[c*160+k], s);
    if (n < 320) dh[o] = f2bf(s);
    else         tmp[(n-320)*160 + k] = s;
}

__global__ void prep_H_fold(const float* __restrict__ fo, const float* __restrict__ Hv,
                            ushort* __restrict__ dh)
{
    int o = blockIdx.x*NTH + threadIdx.x;
    if (o >= 25600) return;
    int n = o/160, k = o - n*160;
    float s = 0.f;
    for (int j=0;j<160;j++) s = fmaf(fo[n*160+j], Hv[j*160+k], s);
    dh[(320+n)*160 + k] = f2bf(s);
}

__global__ void prep_cvec(const float* __restrict__ f_in_w, const float* __restrict__ out_b,
                          const float* __restrict__ f_in_b, float* __restrict__ cvt)
{
    int n = blockIdx.x*NTH + threadIdx.x;
    if (n >= 480) return;
    float s = f_in_b[n];
    for (int c=0;c<160;c++) s = fmaf(f_in_w[n*160+c], out_b[c], s);
    cvt[n] = s;
}

__global__ void prep_cvec_fold(const float* __restrict__ fo, const float* __restrict__ cvt,
                               float* __restrict__ cv)
{
    int n = blockIdx.x*NTH + threadIdx.x;
    if (n >= 480) return;
    if (n < 320){ cv[n] = cvt[n]; return; }
    int m = n - 320;
    float s = 0.f;
    for (int j=0;j<160;j++) s = fmaf(fo[m*160+j], cvt[320+j], s);
    cv[n] = s;
}

__global__ void prep_conv_bf1(const float* __restrict__ src, ushort* __restrict__ dh, int n)
{
    int o = blockIdx.x*NTH + threadIdx.x;
    if (o >= n) return;
    dh[o] = f2bf(src[o]);
}

__global__ void prep_conv_bf2(const float* __restrict__ src,
                              ushort* __restrict__ dh, ushort* __restrict__ dl, int n)
{
    int o = blockIdx.x*NTH + threadIdx.x;
    if (o >= n) return;
    float s = src[o];
    ushort h = f2bf(s);
    dh[o] = h; dl[o] = f2bf(s - bf2f(h));
}

// ============================ MFMA GEMM (fp32 A, split-x3) — final linear ============
__global__ __launch_bounds__(NTH)
void gemm_mfma_lin(const float* __restrict__ A,
                   const ushort* __restrict__ Wh, const ushort* __restrict__ Wl,
                   const float* __restrict__ bias, float* __restrict__ C, int N)
{
    __shared__ ushort sAh[128*40], sAl[128*40];
    __shared__ ushort sWh[160*40], sWl[160*40];

    const int tid = threadIdx.x;
    const int lane = tid & 63, wave = tid >> 6;
    const int wm = wave >> 1, wn = wave & 1;
    const int ln = lane & 15, g = lane >> 4;
    const long m0 = (long)blockIdx.x * 128;
    const int  n0 = blockIdx.y * 160;

    f32x4 acc[4][5];
#pragma unroll
    for (int mt=0;mt<4;mt++)
#pragma unroll
        for (int nt=0;nt<5;nt++)
#pragma unroll
            for (int r=0;r<4;r++) acc[mt][nt][r] = 0.f;

    for (int k0=0;k0<160;k0+=32){
#pragma unroll
        for (int i=0;i<4;i++){
            int f = tid + 256*i;
            int m = f >> 3, seg = f & 7;
            float4 v = *(const float4*)(A + (m0+m)*160 + k0 + seg*4);
            ushort4 hv, lv;
            hv.x = f2bf(v.x); lv.x = f2bf(v.x - bf2f(hv.x));
            hv.y = f2bf(v.y); lv.y = f2bf(v.y - bf2f(hv.y));
            hv.z = f2bf(v.z); lv.z = f2bf(v.z - bf2f(hv.z));
            hv.w = f2bf(v.w); lv.w = f2bf(v.w - bf2f(hv.w));
            *(ushort4*)(sAh + m*40 + seg*4) = hv;
            *(ushort4*)(sAl + m*40 + seg*4) = lv;
        }
#pragma unroll
        for (int i=0;i<5;i++){
            int e = tid + 256*i;
            int pl = (e >= 640);
            int idx = pl ? e-640 : e;
            int n = idx >> 2, seg = idx & 3;
            const ushort* src = (pl ? Wl : Wh) + (long)(n0+n)*160 + k0 + seg*8;
            ushort* dst = (pl ? sWl : sWh) + n*40 + seg*8;
            *(uint4*)dst = *(const uint4*)src;
        }
        __syncthreads();

        bf16x8 ah[4], al[4];
#pragma unroll
        for (int mt=0;mt<4;mt++){
            int off = (wm*64 + mt*16 + ln)*40 + g*8;
            ah[mt] = *(const bf16x8*)(sAh + off);
            al[mt] = *(const bf16x8*)(sAl + off);
        }
#pragma unroll
        for (int nt=0;nt<5;nt++){
            int offw = (wn*80 + nt*16 + ln)*40 + g*8;
            bf16x8 bh = *(const bf16x8*)(sWh + offw);
            bf16x8 bl = *(const bf16x8*)(sWl + offw);
#pragma unroll
            for (int mt=0;mt<4;mt++){
                acc[mt][nt] = __builtin_amdgcn_mfma_f32_16x16x32_bf16(ah[mt], bh, acc[mt][nt], 0,0,0);
                acc[mt][nt] = __builtin_amdgcn_mfma_f32_16x16x32_bf16(al[mt], bh, acc[mt][nt], 0,0,0);
                acc[mt][nt] = __builtin_amdgcn_mfma_f32_16x16x32_bf16(ah[mt], bl, acc[mt][nt], 0,0,0);
            }
        }
        __syncthreads();
    }

#pragma unroll
    for (int nt=0;nt<5;nt++){
        int col = n0 + wn*80 + nt*16 + ln;
        float bv = bias[col];
#pragma unroll
        for (int mt=0;mt<4;mt++){
#pragma unroll
            for (int r=0;r<4;r++){
                long row = m0 + wm*64 + mt*16 + g*4 + r;
                float x = acc[mt][nt][r] + bv;
                x = x > 0.f ? x : expm1f(x);
                C[row*N + col] = x;
            }
        }
    }
}

// ============================ bf16 GEMM (A bf16, W single-plane) ============
// LDS-bounce epilogue: full-line coalesced bf16 stores.
__global__ __launch_bounds__(NTH)
void gemm_bf(const ushort* __restrict__ A0, const ushort* __restrict__ A1,
             const ushort* __restrict__ Wh0, const ushort* __restrict__ Wh1,
             const float* __restrict__ b0, const float* __restrict__ b1,
             ushort* __restrict__ C0, ushort* __restrict__ C1, int N)
{
    const int z = blockIdx.z;
    const ushort* A  = z ? A1 : A0;
    const ushort* Wh = z ? Wh1 : Wh0;
    const float* bias = z ? b1 : b0;
    ushort* C = z ? C1 : C0;

    __shared__ ushort smem[11520];     // sA 128*40 | sW 160*40 ; reused as sE 64*168
    ushort* sA = smem;
    ushort* sW = smem + 5120;
    ushort* sE = smem;

    const int tid = threadIdx.x;
    const int lane = tid & 63, wave = tid >> 6;
    const int wm = wave >> 1, wn = wave & 1;
    const int ln = lane & 15, g = lane >> 4;
    const long m0 = (long)blockIdx.x * 128;
    const int  n0 = blockIdx.y * 160;

    f32x4 acc[4][5];
#pragma unroll
    for (int mt=0;mt<4;mt++)
#pragma unroll
        for (int nt=0;nt<5;nt++)
#pragma unroll
            for (int r=0;r<4;r++) acc[mt][nt][r] = 0.f;

    for (int k0=0;k0<160;k0+=32){
#pragma unroll
        for (int i=0;i<2;i++){
            int e = tid + 256*i;
            int m = e >> 2, seg = e & 3;
            *(uint4*)(sA + m*40 + seg*8) =
                *(const uint4*)(A + (m0+m)*160 + k0 + seg*8);
        }
#pragma unroll
        for (int i=0;i<3;i++){
            int e = tid + 256*i;
            if (e < 640){
                int n = e >> 2, seg = e & 3;
                *(uint4*)(sW + n*40 + seg*8) =
                    *(const uint4*)(Wh + (long)(n0+n)*160 + k0 + seg*8);
            }
        }
        __syncthreads();

        bf16x8 af[4];
#pragma unroll
        for (int mt=0;mt<4;mt++)
            af[mt] = *(const bf16x8*)(sA + (wm*64 + mt*16 + ln)*40 + g*8);
#pragma unroll
        for (int nt=0;nt<5;nt++){
            bf16x8 bh = *(const bf16x8*)(sW + (wn*80 + nt*16 + ln)*40 + g*8);
#pragma unroll
            for (int mt=0;mt<4;mt++)
                acc[mt][nt] = __builtin_amdgcn_mfma_f32_16x16x32_bf16(af[mt], bh, acc[mt][nt], 0,0,0);
        }
        __syncthreads();
    }

    // epilogue: bounce through LDS, 2 passes of 64 rows, flush as uint4 lines
#pragma unroll
    for (int p=0;p<2;p++){
        if (wm == p){
#pragma unroll
            for (int nt=0;nt<5;nt++){
                int col = wn*80 + nt*16 + ln;
                float bv = bias[n0 + col];
#pragma unroll
                for (int mt=0;mt<4;mt++)
#pragma unroll
                    for (int r=0;r<4;r++)
                        sE[(mt*16 + g*4 + r)*168 + col] = f2bf(acc[mt][nt][r] + bv);
            }
        }
        __syncthreads();
#pragma unroll
        for (int i=0;i<5;i++){
            int e = tid + 256*i;
            int m = e/20, c = e - m*20;
            *(uint4*)(C + (m0 + p*64 + m)*(long)N + n0 + c*8) =
                *(const uint4*)(sE + m*168 + c*8);
        }
        __syncthreads();
    }
}

// ============================ MFMA attention, layers 1/2 ============
// O written via LDS staging (full-line stores).
__global__ __launch_bounds__(64)
void attn_layer_mfma(const ushort* __restrict__ XPi, const ushort* __restrict__ XPo,
                     const int* __restrict__ in_idx, const int* __restrict__ out_idx,
                     ushort* __restrict__ Oi, ushort* __restrict__ Oo, int node_base)
{
    const ushort* XP = blockIdx.y ? XPo : XPi;
    const int*  idx  = blockIdx.y ? out_idx : in_idx;
    ushort* O        = blockIdx.y ? Oo : Oi;

    __shared__ ushort XPg[16*496];
    __shared__ ushort Pall[5*16*24];
    __shared__ ushort sO[16*168];

    const int lane = threadIdx.x;
    const int ln = lane & 15, q = lane >> 4;
    const int node = node_base + blockIdx.x;
    const int bb = node >> 12, nn = node & 4095;

    int idxv = nn;
    if (lane >= 1 && lane < 16) idxv = idx[(long)node*15 + lane-1];

#pragma unroll
    for (int i=0;i<15;i++){
        int e = lane + 64*i;
        int r = e/60, c = e - r*60;
        int rowg = __shfl(idxv, r);
        *(uint4*)(XPg + r*496 + c*8) =
            *(const uint4*)(XP + (long)(bb*4096 + rowg)*480 + c*8);
    }
    __syncthreads();

    const float scale = 0.17677669529663687f;
#pragma unroll
    for (int h=0;h<5;h++){
        bf16x8 ka = *(const bf16x8*)(XPg + ln*496 + 160 + h*32 + q*8);
        bf16x8 qb = *(const bf16x8*)(XPg + ln*496 +       h*32 + q*8);
        f32x4 s = {0.f,0.f,0.f,0.f};
        s = __builtin_amdgcn_mfma_f32_16x16x32_bf16(ka, qb, s, 0,0,0);
        float x[4], m = -1e30f;
#pragma unroll
        for (int r=0;r<4;r++){ x[r] = s[r]*scale; m = fmaxf(m, x[r]); }
        m = fmaxf(m, __shfl_xor(m, 16));
        m = fmaxf(m, __shfl_xor(m, 32));
        float e0[4], sum = 0.f;
#pragma unroll
        for (int r=0;r<4;r++){ e0[r] = __expf(x[r]-m); sum += e0[r]; }
        sum += __shfl_xor(sum, 16);
        sum += __shfl_xor(sum, 32);
        float inv = 1.f/sum;
        ushort4 pw;
        pw.x = f2bf(e0[0]*inv); pw.y = f2bf(e0[1]*inv);
        pw.z = f2bf(e0[2]*inv); pw.w = f2bf(e0[3]*inv);
        *(ushort4*)(Pall + h*384 + ln*24 + q*4) = pw;
    }
    __syncthreads();

#pragma unroll
    for (int h=0;h<5;h++){
        u16x8 ta;
#pragma unroll
        for (int jj=0;jj<8;jj++) ta[jj] = 0;
        if (q < 2) ta = *(const u16x8*)(Pall + h*384 + ln*24 + q*8);
        bf16x8 ap = *(bf16x8*)&ta;
#pragma unroll
        for (int half=0; half<2; half++){
            u16x8 tb;
#pragma unroll
            for (int jj=0;jj<8;jj++) tb[jj] = 0;
            if (q < 2){
#pragma unroll
                for (int jj=0;jj<8;jj++)
                    tb[jj] = XPg[(q*8+jj)*496 + 320 + h*32 + half*16 + ln];
            }
            bf16x8 bv = *(bf16x8*)&tb;
            f32x4 o = {0.f,0.f,0.f,0.f};
            o = __builtin_amdgcn_mfma_f32_16x16x32_bf16(ap, bv, o, 0,0,0);
#pragma unroll
            for (int r=0;r<4;r++)
                sO[(q*4 + r)*168 + h*32 + half*16 + ln] = f2bf(o[r]);
        }
    }
    __syncthreads();

    // flush O: 16 rows x 160 = 320 uint4, fully coalesced
#pragma unroll
    for (int i=0;i<5;i++){
        int e = lane + 64*i;
        int r = e/20, c = e - r*20;
        *(uint4*)(O + (long)(blockIdx.x*16 + r)*160 + c*8) =
            *(const uint4*)(sO + r*168 + c*8);
    }
}

// ============================ MFMA final attention + fused max-pool ============
__global__ __launch_bounds__(64)
void attn_final_pool(const ushort* __restrict__ FQi, const ushort* __restrict__ FQo,
                     const float* __restrict__ fb, float* __restrict__ pooled,
                     int node_base)
{
    __shared__ ushort F[32*328];
    __shared__ ushort P[32*40];

    const int lane = threadIdx.x;
    const int ln = lane & 15, q = lane >> 4;
    const int nl = blockIdx.x;

#pragma unroll
    for (int i=0;i<20;i++){
        int e = lane + 64*i;
        int r = e/40, c = e - r*40;
        const ushort* src = (r<16) ? (FQi + (long)(nl*16+r)*480 + c*8)
                                   : (FQo + (long)(nl*16+r-16)*480 + c*8);
        *(uint4*)(F + r*328 + c*8) = *(const uint4*)src;
    }
    __syncthreads();

    f32x4 sc[2][2];
#pragma unroll
    for (int ti=0;ti<2;ti++)
#pragma unroll
        for (int tj=0;tj<2;tj++){
            f32x4 a = {0.f,0.f,0.f,0.f};
#pragma unroll
            for (int kc=0;kc<5;kc++){
                bf16x8 ka = *(const bf16x8*)(F + (tj*16+ln)*328 + 160 + kc*32 + q*8);
                bf16x8 qb = *(const bf16x8*)(F + (ti*16+ln)*328 +       kc*32 + q*8);
                a = __builtin_amdgcn_mfma_f32_16x16x32_bf16(ka, qb, a, 0,0,0);
            }
            sc[ti][tj] = a;
        }

    const float scale = 0.07905694150420949f;
#pragma unroll
    for (int ti=0;ti<2;ti++){
        float x[2][4], m = -1e30f;
#pragma unroll
        for (int tj=0;tj<2;tj++)
#pragma unroll
            for (int r=0;r<4;r++){ x[tj][r] = sc[ti][tj][r]*scale; m = fmaxf(m, x[tj][r]); }
        m = fmaxf(m, __shfl_xor(m, 16));
        m = fmaxf(m, __shfl_xor(m, 32));
        float sum = 0.f;
#pragma unroll
        for (int tj=0;tj<2;tj++)
#pragma unroll
            for (int r=0;r<4;r++){ x[tj][r] = __expf(x[tj][r]-m); sum += x[tj][r]; }
        sum += __shfl_xor(sum, 16);
        sum += __shfl_xor(sum, 32);
        float inv = 1.f/sum;
#pragma unroll
        for (int tj=0;tj<2;tj++){
            ushort4 pw;
            pw.x = f2bf(x[tj][0]*inv); pw.y = f2bf(x[tj][1]*inv);
            pw.z = f2bf(x[tj][2]*inv); pw.w = f2bf(x[tj][3]*inv);
            *(ushort4*)(P + (ti*16+ln)*40 + tj*16 + q*4) = pw;
        }
    }
    __syncthreads();

#pragma unroll
    for (int i=0;i<10;i++){
        int e = lane + 64*i;
        int r = e/20, c = e - r*20;
        const ushort* src = (r<16) ? (FQi + (long)(nl*16+r)*480 + 320 + c*8)
                                   : (FQo + (long)(nl*16+r-16)*480 + 320 + c*8);
        *(uint4*)(F + r*168 + c*8) = *(const uint4*)src;
    }
    __syncthreads();

    bf16x8 ap[2];
#pragma unroll
    for (int mi=0;mi<2;mi++)
        ap[mi] = *(const bf16x8*)(P + (mi*16+ln)*40 + q*8);

    const int node = node_base + nl;
#pragma unroll
    for (int nt=0;nt<10;nt++){
        u16x8 tb;
#pragma unroll
        for (int jj=0;jj<8;jj++) tb[jj] = F[(q*8+jj)*168 + nt*16 + ln];
        bf16x8 bv = *(bf16x8*)&tb;
        float vmax = -1e30f;
#pragma unroll
        for (int mi=0;mi<2;mi++){
            f32x4 o = {0.f,0.f,0.f,0.f};
            o = __builtin_amdgcn_mfma_f32_16x16x32_bf16(ap[mi], bv, o, 0,0,0);
#pragma unroll
            for (int r=0;r<4;r++) vmax = fmaxf(vmax, o[r]);
        }
        vmax = fmaxf(vmax, __shfl_xor(vmax, 16));
        vmax = fmaxf(vmax, __shfl_xor(vmax, 32));
        if (q == 0){
            int col = nt*16 + ln;
            pooled[(long)node*160 + col] = vmax + fb[col];
        }
    }
}

// ============================ host ============================
extern "C" void kernel_launch(void* const* d_in, const int* in_sizes, int n_in,
                              void* d_out, int out_size, void* d_ws, size_t ws_size,
                              hipStream_t stream)
{
    const float* X       = (const float*)d_in[0];
    const int*   in_idx  = (const int*)  d_in[1];
    const int*   out_idx = (const int*)  d_in[2];
    const float* iWq     = (const float*)d_in[3];
    const float* iWk     = (const float*)d_in[4];
    const float* iWv     = (const float*)d_in[5];
    const float* i_in_w  = (const float*)d_in[6];
    const float* i_in_b  = (const float*)d_in[7];
    const float* i_out_w = (const float*)d_in[8];
    const float* i_out_b = (const float*)d_in[9];
    const float* oWq     = (const float*)d_in[10];
    const float* oWk     = (const float*)d_in[11];
    const float* oWv     = (const float*)d_in[12];
    const float* o_in_w  = (const float*)d_in[13];
    const float* o_in_b  = (const float*)d_in[14];
    const float* o_out_w = (const float*)d_in[15];
    const float* o_out_b = (const float*)d_in[16];
    const float* f_in_w  = (const float*)d_in[17];
    const float* f_in_b  = (const float*)d_in[18];
    const float* f_out_w = (const float*)d_in[19];
    const float* f_out_b = (const float*)d_in[20];
    const float* lin_w   = (const float*)d_in[21];
    const float* lin_b   = (const float*)d_in[22];

    float* ws = (float*)d_ws;
    float* pooled = ws;                           // 32768*160 fp32
    float* c_i    = pooled + 5242880;             // 480 (folded)
    float* c_o    = c_i + 480;
    float* cvt_i  = c_o + 480;                    // 480 raw
    float* cvt_o  = cvt_i + 480;
    float* Hvt_i  = cvt_o + 480;                  // 160x160 fp32
    float* Hvt_o  = Hvt_i + 25600;
    ushort* ub    = (ushort*)(Hvt_o + 25600);
    ushort* Xb    = ub;                           // 32768*160 bf16
    ushort* XPb_i = Xb + 5242880;                 // 32768*480 bf16
    ushort* XPb_o = XPb_i + 15728640;
    ushort* Wci_h = XPb_o + 15728640;             // 76800 each
    ushort* Wco_h = Wci_h + 76800;
    ushort* Hi_h  = Wco_h + 76800;
    ushort* Ho_h  = Hi_h  + 76800;
    ushort* li_h  = Ho_h  + 76800;                // 25600 each
    ushort* li_l  = li_h  + 25600;
    ushort* sb_us = li_l + 25600;
    const unsigned long long fixed = 23825280ULL;

    size_t avail = ws_size / 4;
    int ns = 4096;                                // slice for L3 residency
    while (ns > 64 && fixed + 10240ULL*ns > avail) ns >>= 1;

    ushort* O_i = sb_us;                          // ns*16*160
    ushort* O_o = O_i + (size_t)2560*ns;
    ushort* FQi = O_o + (size_t)2560*ns;          // ns*16*480
    ushort* FQo = FQi + (size_t)7680*ns;

    prep_combined_bf<<<300,NTH,0,stream>>>(iWq,iWk,iWv,i_in_w, Wci_h);
    prep_combined_bf<<<300,NTH,0,stream>>>(oWq,oWk,oWv,o_in_w, Wco_h);
    prep_H_split<<<300,NTH,0,stream>>>(f_in_w, i_out_w, Hi_h, Hvt_i);
    prep_H_split<<<300,NTH,0,stream>>>(f_in_w, o_out_w, Ho_h, Hvt_o);
    prep_H_fold<<<100,NTH,0,stream>>>(f_out_w, Hvt_i, Hi_h);
    prep_H_fold<<<100,NTH,0,stream>>>(f_out_w, Hvt_o, Ho_h);
    prep_cvec<<<2,NTH,0,stream>>>(f_in_w, i_out_b, f_in_b, cvt_i);
    prep_cvec<<<2,NTH,0,stream>>>(f_in_w, o_out_b, f_in_b, cvt_o);
    prep_cvec_fold<<<2,NTH,0,stream>>>(f_out_w, cvt_i, c_i);
    prep_cvec_fold<<<2,NTH,0,stream>>>(f_out_w, cvt_o, c_o);
    prep_conv_bf2<<<100,NTH,0,stream>>>(lin_w, li_h, li_l, 25600);
    prep_conv_bf1<<<20480,NTH,0,stream>>>(X, Xb, 5242880);

    // XP = Xb @ Wc^T + in_b  -> bf16 (both layers via z)
    dim3 g1(256, 3, 2);
    gemm_bf<<<g1,NTH,0,stream>>>(Xb, Xb, Wci_h, Wco_h, i_in_b, o_in_b,
                                 XPb_i, XPb_o, 480);

    int S = 32768 / ns;
    for (int s=0;s<S;s++){
        int base = s*ns;
        dim3 ga(ns, 2);
        attn_layer_mfma<<<ga,64,0,stream>>>(XPb_i, XPb_o, in_idx, out_idx, O_i, O_o, base);
        dim3 g3(ns/8, 3, 2);
        gemm_bf<<<g3,NTH,0,stream>>>(O_i, O_o, Hi_h, Ho_h, c_i, c_o, FQi, FQo, 480);
        attn_final_pool<<<ns,64,0,stream>>>(FQi, FQo, f_out_b, pooled, base);
    }

    // out = ELU(pooled @ lin_w^T + lin_b)  fp32, split-x3
    dim3 g6(256, 1);
    gemm_mfma_lin<<<g6,NTH,0,stream>>>(pooled, li_h, li_l, lin_b, (float*)d_out, 160);
}

// Round 13
// 1301.898 us; speedup vs baseline: 1.0546x; 1.0546x over previous
//
#include <hip/hip_runtime.h>
#include <hip/hip_bf16.h>
#include <math.h>

#define NTH 256

typedef __bf16 bf16x8 __attribute__((ext_vector_type(8)));
typedef float  f32x4  __attribute__((ext_vector_type(4)));
typedef unsigned short ushort;
typedef ushort u16x8 __attribute__((ext_vector_type(8)));

__device__ __forceinline__ ushort f2bf(float x){
    union { float f; unsigned int u; } v; v.f = x;
    unsigned int r = v.u + 0x7fffu + ((v.u >> 16) & 1u);
    return (ushort)(r >> 16);
}
__device__ __forceinline__ float bf2f(ushort h){
    union { unsigned int u; float f; } v; v.u = ((unsigned int)h) << 16;
    return v.f;
}

// ============================ prep kernels ============================
__global__ void prep_combined_bf(const float* __restrict__ Wq, const float* __restrict__ Wk,
                                 const float* __restrict__ Wv, const float* __restrict__ in_w,
                                 ushort* __restrict__ dh)
{
    int o = blockIdx.x*NTH + threadIdx.x;
    if (o >= 76800) return;
    int c = o/160, j = o - c*160;
    const float* Wsel = (c<160) ? Wq : (c<320) ? Wk : Wv;
    const float* wrow = Wsel + j*160;
    const float* irow = in_w + c*160;
    float s = 0.f;
    for (int k=0;k<160;k++) s = fmaf(wrow[k], irow[k], s);
    dh[o] = f2bf(s);
}

__global__ void prep_H_split(const float* __restrict__ f_in_w, const float* __restrict__ out_w,
                             ushort* __restrict__ dh, float* __restrict__ tmp)
{
    int o = blockIdx.x*NTH + threadIdx.x;
    if (o >= 76800) return;
    int n = o/160, k = o - n*160;
    float s = 0.f;
    for (int c=0;c<160;c++) s = fmaf(f_in_w[n*160+c], out_w[c*160+k], s);
    if (n < 320) dh[o] = f2bf(s);
    else         tmp[(n-320)*160 + k] = s;
}

__global__ void prep_H_fold(const float* __restrict__ fo, const float* __restrict__ Hv,
                            ushort* __restrict__ dh)
{
    int o = blockIdx.x*NTH + threadIdx.x;
    if (o >= 25600) return;
    int n = o/160, k = o - n*160;
    float s = 0.f;
    for (int j=0;j<160;j++) s = fmaf(fo[n*160+j], Hv[j*160+k], s);
    dh[(320+n)*160 + k] = f2bf(s);
}

__global__ void prep_cvec(const float* __restrict__ f_in_w, const float* __restrict__ out_b,
                          const float* __restrict__ f_in_b, float* __restrict__ cvt)
{
    int n = blockIdx.x*NTH + threadIdx.x;
    if (n >= 480) return;
    float s = f_in_b[n];
    for (int c=0;c<160;c++) s = fmaf(f_in_w[n*160+c], out_b[c], s);
    cvt[n] = s;
}

__global__ void prep_cvec_fold(const float* __restrict__ fo, const float* __restrict__ cvt,
                               float* __restrict__ cv)
{
    int n = blockIdx.x*NTH + threadIdx.x;
    if (n >= 480) return;
    if (n < 320){ cv[n] = cvt[n]; return; }
    int m = n - 320;
    float s = 0.f;
    for (int j=0;j<160;j++) s = fmaf(fo[m*160+j], cvt[320+j], s);
    cv[n] = s;
}

__global__ void prep_conv_bf1(const float* __restrict__ src, ushort* __restrict__ dh, int n)
{
    int o = blockIdx.x*NTH + threadIdx.x;
    if (o >= n) return;
    dh[o] = f2bf(src[o]);
}

__global__ void prep_conv_bf2(const float* __restrict__ src,
                              ushort* __restrict__ dh, ushort* __restrict__ dl, int n)
{
    int o = blockIdx.x*NTH + threadIdx.x;
    if (o >= n) return;
    float s = src[o];
    ushort h = f2bf(s);
    dh[o] = h; dl[o] = f2bf(s - bf2f(h));
}

// ============================ MFMA GEMM (fp32 A, split-x3) — final linear ============
// Operand-swapped MFMA: lane holds row=lane&15, cols=quad*4+r -> float4 stores.
__global__ __launch_bounds__(NTH)
void gemm_mfma_lin(const float* __restrict__ A,
                   const ushort* __restrict__ Wh, const ushort* __restrict__ Wl,
                   const float* __restrict__ bias, float* __restrict__ C, int N)
{
    __shared__ ushort sAh[128*40], sAl[128*40];
    __shared__ ushort sWh[160*40], sWl[160*40];

    const int tid = threadIdx.x;
    const int lane = tid & 63, wave = tid >> 6;
    const int wm = wave >> 1, wn = wave & 1;
    const int ln = lane & 15, g = lane >> 4;
    const long m0 = (long)blockIdx.x * 128;
    const int  n0 = blockIdx.y * 160;

    f32x4 acc[4][5];
#pragma unroll
    for (int mt=0;mt<4;mt++)
#pragma unroll
        for (int nt=0;nt<5;nt++)
#pragma unroll
            for (int r=0;r<4;r++) acc[mt][nt][r] = 0.f;

    for (int k0=0;k0<160;k0+=32){
#pragma unroll
        for (int i=0;i<4;i++){
            int f = tid + 256*i;
            int m = f >> 3, seg = f & 7;
            float4 v = *(const float4*)(A + (m0+m)*160 + k0 + seg*4);
            ushort4 hv, lv;
            hv.x = f2bf(v.x); lv.x = f2bf(v.x - bf2f(hv.x));
            hv.y = f2bf(v.y); lv.y = f2bf(v.y - bf2f(hv.y));
            hv.z = f2bf(v.z); lv.z = f2bf(v.z - bf2f(hv.z));
            hv.w = f2bf(v.w); lv.w = f2bf(v.w - bf2f(hv.w));
            *(ushort4*)(sAh + m*40 + seg*4) = hv;
            *(ushort4*)(sAl + m*40 + seg*4) = lv;
        }
#pragma unroll
        for (int i=0;i<5;i++){
            int e = tid + 256*i;
            int pl = (e >= 640);
            int idx = pl ? e-640 : e;
            int n = idx >> 2, seg = idx & 3;
            const ushort* src = (pl ? Wl : Wh) + (long)(n0+n)*160 + k0 + seg*8;
            ushort* dst = (pl ? sWl : sWh) + n*40 + seg*8;
            *(uint4*)dst = *(const uint4*)src;
        }
        __syncthreads();

        bf16x8 ah[4], al[4];
#pragma unroll
        for (int mt=0;mt<4;mt++){
            int off = (wm*64 + mt*16 + ln)*40 + g*8;
            ah[mt] = *(const bf16x8*)(sAh + off);
            al[mt] = *(const bf16x8*)(sAl + off);
        }
#pragma unroll
        for (int nt=0;nt<5;nt++){
            int offw = (wn*80 + nt*16 + ln)*40 + g*8;
            bf16x8 bh = *(const bf16x8*)(sWh + offw);
            bf16x8 bl = *(const bf16x8*)(sWl + offw);
#pragma unroll
            for (int mt=0;mt<4;mt++){
                acc[mt][nt] = __builtin_amdgcn_mfma_f32_16x16x32_bf16(bh, ah[mt], acc[mt][nt], 0,0,0);
                acc[mt][nt] = __builtin_amdgcn_mfma_f32_16x16x32_bf16(bh, al[mt], acc[mt][nt], 0,0,0);
                acc[mt][nt] = __builtin_amdgcn_mfma_f32_16x16x32_bf16(bl, ah[mt], acc[mt][nt], 0,0,0);
            }
        }
        __syncthreads();
    }

#pragma unroll
    for (int nt=0;nt<5;nt++){
        int colb = n0 + wn*80 + nt*16 + g*4;
        float4 bv4 = *(const float4*)(bias + colb);
#pragma unroll
        for (int mt=0;mt<4;mt++){
            long row = m0 + wm*64 + mt*16 + ln;
            float4 ov;
            ov.x = acc[mt][nt][0] + bv4.x; ov.x = ov.x > 0.f ? ov.x : expm1f(ov.x);
            ov.y = acc[mt][nt][1] + bv4.y; ov.y = ov.y > 0.f ? ov.y : expm1f(ov.y);
            ov.z = acc[mt][nt][2] + bv4.z; ov.z = ov.z > 0.f ? ov.z : expm1f(ov.z);
            ov.w = acc[mt][nt][3] + bv4.w; ov.w = ov.w > 0.f ? ov.w : expm1f(ov.w);
            *(float4*)(C + row*N + colb) = ov;
        }
    }
}

// ============================ bf16 GEMM (A bf16, W single-plane) ============
// Operand-swapped MFMA -> packed ushort4 stores (20 per thread, no barriers).
__global__ __launch_bounds__(NTH)
void gemm_bf(const ushort* __restrict__ A0, const ushort* __restrict__ A1,
             const ushort* __restrict__ Wh0, const ushort* __restrict__ Wh1,
             const float* __restrict__ b0, const float* __restrict__ b1,
             ushort* __restrict__ C0, ushort* __restrict__ C1, int N)
{
    const int z = blockIdx.z;
    const ushort* A  = z ? A1 : A0;
    const ushort* Wh = z ? Wh1 : Wh0;
    const float* bias = z ? b1 : b0;
    ushort* C = z ? C1 : C0;

    __shared__ ushort sA[128*40];
    __shared__ ushort sW[160*40];

    const int tid = threadIdx.x;
    const int lane = tid & 63, wave = tid >> 6;
    const int wm = wave >> 1, wn = wave & 1;
    const int ln = lane & 15, g = lane >> 4;
    const long m0 = (long)blockIdx.x * 128;
    const int  n0 = blockIdx.y * 160;

    f32x4 acc[4][5];
#pragma unroll
    for (int mt=0;mt<4;mt++)
#pragma unroll
        for (int nt=0;nt<5;nt++)
#pragma unroll
            for (int r=0;r<4;r++) acc[mt][nt][r] = 0.f;

    for (int k0=0;k0<160;k0+=32){
#pragma unroll
        for (int i=0;i<2;i++){
            int e = tid + 256*i;
            int m = e >> 2, seg = e & 3;
            *(uint4*)(sA + m*40 + seg*8) =
                *(const uint4*)(A + (m0+m)*160 + k0 + seg*8);
        }
#pragma unroll
        for (int i=0;i<3;i++){
            int e = tid + 256*i;
            if (e < 640){
                int n = e >> 2, seg = e & 3;
                *(uint4*)(sW + n*40 + seg*8) =
                    *(const uint4*)(Wh + (long)(n0+n)*160 + k0 + seg*8);
            }
        }
        __syncthreads();

        bf16x8 af[4];
#pragma unroll
        for (int mt=0;mt<4;mt++)
            af[mt] = *(const bf16x8*)(sA + (wm*64 + mt*16 + ln)*40 + g*8);
#pragma unroll
        for (int nt=0;nt<5;nt++){
            bf16x8 bh = *(const bf16x8*)(sW + (wn*80 + nt*16 + ln)*40 + g*8);
#pragma unroll
            for (int mt=0;mt<4;mt++)
                acc[mt][nt] = __builtin_amdgcn_mfma_f32_16x16x32_bf16(bh, af[mt], acc[mt][nt], 0,0,0);
        }
        __syncthreads();
    }

#pragma unroll
    for (int nt=0;nt<5;nt++){
        int colb = n0 + wn*80 + nt*16 + g*4;
        float4 bv4 = *(const float4*)(bias + colb);
#pragma unroll
        for (int mt=0;mt<4;mt++){
            long row = m0 + wm*64 + mt*16 + ln;
            ushort4 pw;
            pw.x = f2bf(acc[mt][nt][0] + bv4.x);
            pw.y = f2bf(acc[mt][nt][1] + bv4.y);
            pw.z = f2bf(acc[mt][nt][2] + bv4.z);
            pw.w = f2bf(acc[mt][nt][3] + bv4.w);
            *(ushort4*)(C + row*(long)N + colb) = pw;
        }
    }
}

// ============================ MFMA attention, layers 1/2 ============
// PV operand-swapped: lane holds row=ln, 4 consecutive cols -> ushort4 stores.
__global__ __launch_bounds__(64)
void attn_layer_mfma(const ushort* __restrict__ XPi, const ushort* __restrict__ XPo,
                     const int* __restrict__ in_idx, const int* __restrict__ out_idx,
                     ushort* __restrict__ Oi, ushort* __restrict__ Oo, int node_base)
{
    const ushort* XP = blockIdx.y ? XPo : XPi;
    const int*  idx  = blockIdx.y ? out_idx : in_idx;
    ushort* O        = blockIdx.y ? Oo : Oi;

    __shared__ ushort XPg[16*496];
    __shared__ ushort Pall[5*16*24];

    const int lane = threadIdx.x;
    const int ln = lane & 15, q = lane >> 4;
    const int node = node_base + blockIdx.x;
    const int bb = node >> 12, nn = node & 4095;

    int idxv = nn;
    if (lane >= 1 && lane < 16) idxv = idx[(long)node*15 + lane-1];

#pragma unroll
    for (int i=0;i<15;i++){
        int e = lane + 64*i;
        int r = e/60, c = e - r*60;
        int rowg = __shfl(idxv, r);
        *(uint4*)(XPg + r*496 + c*8) =
            *(const uint4*)(XP + (long)(bb*4096 + rowg)*480 + c*8);
    }
    __syncthreads();

    const float scale = 0.17677669529663687f;
#pragma unroll
    for (int h=0;h<5;h++){
        bf16x8 ka = *(const bf16x8*)(XPg + ln*496 + 160 + h*32 + q*8);
        bf16x8 qb = *(const bf16x8*)(XPg + ln*496 +       h*32 + q*8);
        f32x4 s = {0.f,0.f,0.f,0.f};
        s = __builtin_amdgcn_mfma_f32_16x16x32_bf16(ka, qb, s, 0,0,0);
        float x[4], m = -1e30f;
#pragma unroll
        for (int r=0;r<4;r++){ x[r] = s[r]*scale; m = fmaxf(m, x[r]); }
        m = fmaxf(m, __shfl_xor(m, 16));
        m = fmaxf(m, __shfl_xor(m, 32));
        float e0[4], sum = 0.f;
#pragma unroll
        for (int r=0;r<4;r++){ e0[r] = __expf(x[r]-m); sum += e0[r]; }
        sum += __shfl_xor(sum, 16);
        sum += __shfl_xor(sum, 32);
        float inv = 1.f/sum;
        ushort4 pw;
        pw.x = f2bf(e0[0]*inv); pw.y = f2bf(e0[1]*inv);
        pw.z = f2bf(e0[2]*inv); pw.w = f2bf(e0[3]*inv);
        *(ushort4*)(Pall + h*384 + ln*24 + q*4) = pw;
    }
    __syncthreads();

#pragma unroll
    for (int h=0;h<5;h++){
        u16x8 ta;
#pragma unroll
        for (int jj=0;jj<8;jj++) ta[jj] = 0;
        if (q < 2) ta = *(const u16x8*)(Pall + h*384 + ln*24 + q*8);
        bf16x8 ap = *(bf16x8*)&ta;
#pragma unroll
        for (int half=0; half<2; half++){
            u16x8 tb;
#pragma unroll
            for (int jj=0;jj<8;jj++) tb[jj] = 0;
            if (q < 2){
#pragma unroll
                for (int jj=0;jj<8;jj++)
                    tb[jj] = XPg[(q*8+jj)*496 + 320 + h*32 + half*16 + ln];
            }
            bf16x8 bv = *(bf16x8*)&tb;
            f32x4 o = {0.f,0.f,0.f,0.f};
            o = __builtin_amdgcn_mfma_f32_16x16x32_bf16(bv, ap, o, 0,0,0);
            // lane: row = ln, cols = h*32 + half*16 + q*4 .. +3
            ushort4 pw;
            pw.x = f2bf(o[0]); pw.y = f2bf(o[1]);
            pw.z = f2bf(o[2]); pw.w = f2bf(o[3]);
            *(ushort4*)(O + (long)(blockIdx.x*16 + ln)*160 + h*32 + half*16 + q*4) = pw;
        }
    }
}

// ============================ MFMA final attention + fused max-pool ============
// (kept col-per-lane orientation: better for the shuffle pool)
__global__ __launch_bounds__(64)
void attn_final_pool(const ushort* __restrict__ FQi, const ushort* __restrict__ FQo,
                     const float* __restrict__ fb, float* __restrict__ pooled,
                     int node_base)
{
    __shared__ ushort F[32*328];
    __shared__ ushort P[32*40];

    const int lane = threadIdx.x;
    const int ln = lane & 15, q = lane >> 4;
    const int nl = blockIdx.x;

#pragma unroll
    for (int i=0;i<20;i++){
        int e = lane + 64*i;
        int r = e/40, c = e - r*40;
        const ushort* src = (r<16) ? (FQi + (long)(nl*16+r)*480 + c*8)
                                   : (FQo + (long)(nl*16+r-16)*480 + c*8);
        *(uint4*)(F + r*328 + c*8) = *(const uint4*)src;
    }
    __syncthreads();

    f32x4 sc[2][2];
#pragma unroll
    for (int ti=0;ti<2;ti++)
#pragma unroll
        for (int tj=0;tj<2;tj++){
            f32x4 a = {0.f,0.f,0.f,0.f};
#pragma unroll
            for (int kc=0;kc<5;kc++){
                bf16x8 ka = *(const bf16x8*)(F + (tj*16+ln)*328 + 160 + kc*32 + q*8);
                bf16x8 qb = *(const bf16x8*)(F + (ti*16+ln)*328 +       kc*32 + q*8);
                a = __builtin_amdgcn_mfma_f32_16x16x32_bf16(ka, qb, a, 0,0,0);
            }
            sc[ti][tj] = a;
        }

    const float scale = 0.07905694150420949f;
#pragma unroll
    for (int ti=0;ti<2;ti++){
        float x[2][4], m = -1e30f;
#pragma unroll
        for (int tj=0;tj<2;tj++)
#pragma unroll
            for (int r=0;r<4;r++){ x[tj][r] = sc[ti][tj][r]*scale; m = fmaxf(m, x[tj][r]); }
        m = fmaxf(m, __shfl_xor(m, 16));
        m = fmaxf(m, __shfl_xor(m, 32));
        float sum = 0.f;
#pragma unroll
        for (int tj=0;tj<2;tj++)
#pragma unroll
            for (int r=0;r<4;r++){ x[tj][r] = __expf(x[tj][r]-m); sum += x[tj][r]; }
        sum += __shfl_xor(sum, 16);
        sum += __shfl_xor(sum, 32);
        float inv = 1.f/sum;
#pragma unroll
        for (int tj=0;tj<2;tj++){
            ushort4 pw;
            pw.x = f2bf(x[tj][0]*inv); pw.y = f2bf(x[tj][1]*inv);
            pw.z = f2bf(x[tj][2]*inv); pw.w = f2bf(x[tj][3]*inv);
            *(ushort4*)(P + (ti*16+ln)*40 + tj*16 + q*4) = pw;
        }
    }
    __syncthreads();

#pragma unroll
    for (int i=0;i<10;i++){
        int e = lane + 64*i;
        int r = e/20, c = e - r*20;
        const ushort* src = (r<16) ? (FQi + (long)(nl*16+r)*480 + 320 + c*8)
                                   : (FQo + (long)(nl*16+r-16)*480 + 320 + c*8);
        *(uint4*)(F + r*168 + c*8) = *(const uint4*)src;
    }
    __syncthreads();

    bf16x8 ap[2];
#pragma unroll
    for (int mi=0;mi<2;mi++)
        ap[mi] = *(const bf16x8*)(P + (mi*16+ln)*40 + q*8);

    const int node = node_base + nl;
#pragma unroll
    for (int nt=0;nt<10;nt++){
        u16x8 tb;
#pragma unroll
        for (int jj=0;jj<8;jj++) tb[jj] = F[(q*8+jj)*168 + nt*16 + ln];
        bf16x8 bv = *(bf16x8*)&tb;
        float vmax = -1e30f;
#pragma unroll
        for (int mi=0;mi<2;mi++){
            f32x4 o = {0.f,0.f,0.f,0.f};
            o = __builtin_amdgcn_mfma_f32_16x16x32_bf16(ap[mi], bv, o, 0,0,0);
#pragma unroll
            for (int r=0;r<4;r++) vmax = fmaxf(vmax, o[r]);
        }
        vmax = fmaxf(vmax, __shfl_xor(vmax, 16));
        vmax = fmaxf(vmax, __shfl_xor(vmax, 32));
        if (q == 0){
            int col = nt*16 + ln;
            pooled[(long)node*160 + col] = vmax + fb[col];
        }
    }
}

// ============================ host ============================
extern "C" void kernel_launch(void* const* d_in, const int* in_sizes, int n_in,
                              void* d_out, int out_size, void* d_ws, size_t ws_size,
                              hipStream_t stream)
{
    const float* X       = (const float*)d_in[0];
    const int*   in_idx  = (const int*)  d_in[1];
    const int*   out_idx = (const int*)  d_in[2];
    const float* iWq     = (const float*)d_in[3];
    const float* iWk     = (const float*)d_in[4];
    const float* iWv     = (const float*)d_in[5];
    const float* i_in_w  = (const float*)d_in[6];
    const float* i_in_b  = (const float*)d_in[7];
    const float* i_out_w = (const float*)d_in[8];
    const float* i_out_b = (const float*)d_in[9];
    const float* oWq     = (const float*)d_in[10];
    const float* oWk     = (const float*)d_in[11];
    const float* oWv     = (const float*)d_in[12];
    const float* o_in_w  = (const float*)d_in[13];
    const float* o_in_b  = (const float*)d_in[14];
    const float* o_out_w = (const float*)d_in[15];
    const float* o_out_b = (const float*)d_in[16];
    const float* f_in_w  = (const float*)d_in[17];
    const float* f_in_b  = (const float*)d_in[18];
    const float* f_out_w = (const float*)d_in[19];
    const float* f_out_b = (const float*)d_in[20];
    const float* lin_w   = (const float*)d_in[21];
    const float* lin_b   = (const float*)d_in[22];

    float* ws = (float*)d_ws;
    float* pooled = ws;                           // 32768*160 fp32
    float* c_i    = pooled + 5242880;             // 480 (folded)
    float* c_o    = c_i + 480;
    float* cvt_i  = c_o + 480;                    // 480 raw
    float* cvt_o  = cvt_i + 480;
    float* Hvt_i  = cvt_o + 480;                  // 160x160 fp32
    float* Hvt_o  = Hvt_i + 25600;
    ushort* ub    = (ushort*)(Hvt_o + 25600);
    ushort* Xb    = ub;                           // 32768*160 bf16
    ushort* XPb_i = Xb + 5242880;                 // 32768*480 bf16
    ushort* XPb_o = XPb_i + 15728640;
    ushort* Wci_h = XPb_o + 15728640;             // 76800 each
    ushort* Wco_h = Wci_h + 76800;
    ushort* Hi_h  = Wco_h + 76800;
    ushort* Ho_h  = Hi_h  + 76800;
    ushort* li_h  = Ho_h  + 76800;                // 25600 each
    ushort* li_l  = li_h  + 25600;
    ushort* sb_us = li_l + 25600;
    const unsigned long long fixed = 23825280ULL;

    size_t avail = ws_size / 4;
    int ns = 32768;
    while (ns > 64 && fixed + 10240ULL*ns > avail) ns >>= 1;

    ushort* O_i = sb_us;                          // ns*16*160
    ushort* O_o = O_i + (size_t)2560*ns;
    ushort* FQi = O_o + (size_t)2560*ns;          // ns*16*480
    ushort* FQo = FQi + (size_t)7680*ns;

    prep_combined_bf<<<300,NTH,0,stream>>>(iWq,iWk,iWv,i_in_w, Wci_h);
    prep_combined_bf<<<300,NTH,0,stream>>>(oWq,oWk,oWv,o_in_w, Wco_h);
    prep_H_split<<<300,NTH,0,stream>>>(f_in_w, i_out_w, Hi_h, Hvt_i);
    prep_H_split<<<300,NTH,0,stream>>>(f_in_w, o_out_w, Ho_h, Hvt_o);
    prep_H_fold<<<100,NTH,0,stream>>>(f_out_w, Hvt_i, Hi_h);
    prep_H_fold<<<100,NTH,0,stream>>>(f_out_w, Hvt_o, Ho_h);
    prep_cvec<<<2,NTH,0,stream>>>(f_in_w, i_out_b, f_in_b, cvt_i);
    prep_cvec<<<2,NTH,0,stream>>>(f_in_w, o_out_b, f_in_b, cvt_o);
    prep_cvec_fold<<<2,NTH,0,stream>>>(f_out_w, cvt_i, c_i);
    prep_cvec_fold<<<2,NTH,0,stream>>>(f_out_w, cvt_o, c_o);
    prep_conv_bf2<<<100,NTH,0,stream>>>(lin_w, li_h, li_l, 25600);
    prep_conv_bf1<<<20480,NTH,0,stream>>>(X, Xb, 5242880);

    // XP = Xb @ Wc^T + in_b  -> bf16 (both layers via z)
    dim3 g1(256, 3, 2);
    gemm_bf<<<g1,NTH,0,stream>>>(Xb, Xb, Wci_h, Wco_h, i_in_b, o_in_b,
                                 XPb_i, XPb_o, 480);

    int S = 32768 / ns;
    for (int s=0;s<S;s++){
        int base = s*ns;
        dim3 ga(ns, 2);
        attn_layer_mfma<<<ga,64,0,stream>>>(XPb_i, XPb_o, in_idx, out_idx, O_i, O_o, base);
        dim3 g3(ns/8, 3, 2);
        gemm_bf<<<g3,NTH,0,stream>>>(O_i, O_o, Hi_h, Ho_h, c_i, c_o, FQi, FQo, 480);
        attn_final_pool<<<ns,64,0,stream>>>(FQi, FQo, f_out_b, pooled, base);
    }

    // out = ELU(pooled @ lin_w^T + lin_b)  fp32, split-x3
    dim3 g6(256, 1);
    gemm_mfma_lin<<<g6,NTH,0,stream>>>(pooled, li_h, li_l, lin_b, (float*)d_out, 160);
}

// Round 14
// 1159.813 us; speedup vs baseline: 1.1838x; 1.1225x over previous
//
#include <hip/hip_runtime.h>
#include <hip/hip_bf16.h>
#include <math.h>

#define NTH 256

typedef __bf16 bf16x8 __attribute__((ext_vector_type(8)));
typedef float  f32x4  __attribute__((ext_vector_type(4)));
typedef unsigned short ushort;
typedef ushort u16x8 __attribute__((ext_vector_type(8)));

__device__ __forceinline__ ushort f2bf(float x){
    union { float f; unsigned int u; } v; v.f = x;
    unsigned int r = v.u + 0x7fffu + ((v.u >> 16) & 1u);
    return (ushort)(r >> 16);
}
__device__ __forceinline__ float bf2f(ushort h){
    union { unsigned int u; float f; } v; v.u = ((unsigned int)h) << 16;
    return v.f;
}

// ============================ prep kernels ============================
__global__ void prep_combined_bf(const float* __restrict__ Wq, const float* __restrict__ Wk,
                                 const float* __restrict__ Wv, const float* __restrict__ in_w,
                                 ushort* __restrict__ dh)
{
    int o = blockIdx.x*NTH + threadIdx.x;
    if (o >= 76800) return;
    int c = o/160, j = o - c*160;
    const float* Wsel = (c<160) ? Wq : (c<320) ? Wk : Wv;
    const float* wrow = Wsel + j*160;
    const float* irow = in_w + c*160;
    float s = 0.f;
    for (int k=0;k<160;k++) s = fmaf(wrow[k], irow[k], s);
    dh[o] = f2bf(s);
}

__global__ void prep_H_split(const float* __restrict__ f_in_w, const float* __restrict__ out_w,
                             ushort* __restrict__ dh, float* __restrict__ tmp)
{
    int o = blockIdx.x*NTH + threadIdx.x;
    if (o >= 76800) return;
    int n = o/160, k = o - n*160;
    float s = 0.f;
    for (int c=0;c<160;c++) s = fmaf(f_in_w[n*160+c], out_w[c*160+k], s);
    if (n < 320) dh[o] = f2bf(s);
    else         tmp[(n-320)*160 + k] = s;
}

__global__ void prep_H_fold(const float* __restrict__ fo, const float* __restrict__ Hv,
                            ushort* __restrict__ dh)
{
    int o = blockIdx.x*NTH + threadIdx.x;
    if (o >= 25600) return;
    int n = o/160, k = o - n*160;
    float s = 0.f;
    for (int j=0;j<160;j++) s = fmaf(fo[n*160+j], Hv[j*160+k], s);
    dh[(320+n)*160 + k] = f2bf(s);
}

__global__ void prep_cvec(const float* __restrict__ f_in_w, const float* __restrict__ out_b,
                          const float* __restrict__ f_in_b, float* __restrict__ cvt)
{
    int n = blockIdx.x*NTH + threadIdx.x;
    if (n >= 480) return;
    float s = f_in_b[n];
    for (int c=0;c<160;c++) s = fmaf(f_in_w[n*160+c], out_b[c], s);
    cvt[n] = s;
}

__global__ void prep_cvec_fold(const float* __restrict__ fo, const float* __restrict__ cvt,
                               float* __restrict__ cv)
{
    int n = blockIdx.x*NTH + threadIdx.x;
    if (n >= 480) return;
    if (n < 320){ cv[n] = cvt[n]; return; }
    int m = n - 320;
    float s = 0.f;
    for (int j=0;j<160;j++) s = fmaf(fo[m*160+j], cvt[320+j], s);
    cv[n] = s;
}

__global__ void prep_conv_bf1(const float* __restrict__ src, ushort* __restrict__ dh, int n)
{
    int o = blockIdx.x*NTH + threadIdx.x;
    if (o >= n) return;
    dh[o] = f2bf(src[o]);
}

__global__ void prep_conv_bf2(const float* __restrict__ src,
                              ushort* __restrict__ dh, ushort* __restrict__ dl, int n)
{
    int o = blockIdx.x*NTH + threadIdx.x;
    if (o >= n) return;
    float s = src[o];
    ushort h = f2bf(s);
    dh[o] = h; dl[o] = f2bf(s - bf2f(h));
}

// ============================ MFMA GEMM (fp32 A, split-x3) — final linear ============
__global__ __launch_bounds__(NTH)
void gemm_mfma_lin(const float* __restrict__ A,
                   const ushort* __restrict__ Wh, const ushort* __restrict__ Wl,
                   const float* __restrict__ bias, float* __restrict__ C, int N)
{
    __shared__ ushort sAh[128*40], sAl[128*40];
    __shared__ ushort sWh[160*40], sWl[160*40];

    const int tid = threadIdx.x;
    const int lane = tid & 63, wave = tid >> 6;
    const int wm = wave >> 1, wn = wave & 1;
    const int ln = lane & 15, g = lane >> 4;
    const long m0 = (long)blockIdx.x * 128;
    const int  n0 = blockIdx.y * 160;

    f32x4 acc[4][5];
#pragma unroll
    for (int mt=0;mt<4;mt++)
#pragma unroll
        for (int nt=0;nt<5;nt++)
#pragma unroll
            for (int r=0;r<4;r++) acc[mt][nt][r] = 0.f;

    for (int k0=0;k0<160;k0+=32){
#pragma unroll
        for (int i=0;i<4;i++){
            int f = tid + 256*i;
            int m = f >> 3, seg = f & 7;
            float4 v = *(const float4*)(A + (m0+m)*160 + k0 + seg*4);
            ushort4 hv, lv;
            hv.x = f2bf(v.x); lv.x = f2bf(v.x - bf2f(hv.x));
            hv.y = f2bf(v.y); lv.y = f2bf(v.y - bf2f(hv.y));
            hv.z = f2bf(v.z); lv.z = f2bf(v.z - bf2f(hv.z));
            hv.w = f2bf(v.w); lv.w = f2bf(v.w - bf2f(hv.w));
            *(ushort4*)(sAh + m*40 + seg*4) = hv;
            *(ushort4*)(sAl + m*40 + seg*4) = lv;
        }
#pragma unroll
        for (int i=0;i<5;i++){
            int e = tid + 256*i;
            int pl = (e >= 640);
            int idx = pl ? e-640 : e;
            int n = idx >> 2, seg = idx & 3;
            const ushort* src = (pl ? Wl : Wh) + (long)(n0+n)*160 + k0 + seg*8;
            ushort* dst = (pl ? sWl : sWh) + n*40 + seg*8;
            *(uint4*)dst = *(const uint4*)src;
        }
        __syncthreads();

        bf16x8 ah[4], al[4];
#pragma unroll
        for (int mt=0;mt<4;mt++){
            int off = (wm*64 + mt*16 + ln)*40 + g*8;
            ah[mt] = *(const bf16x8*)(sAh + off);
            al[mt] = *(const bf16x8*)(sAl + off);
        }
#pragma unroll
        for (int nt=0;nt<5;nt++){
            int offw = (wn*80 + nt*16 + ln)*40 + g*8;
            bf16x8 bh = *(const bf16x8*)(sWh + offw);
            bf16x8 bl = *(const bf16x8*)(sWl + offw);
#pragma unroll
            for (int mt=0;mt<4;mt++){
                acc[mt][nt] = __builtin_amdgcn_mfma_f32_16x16x32_bf16(ah[mt], bh, acc[mt][nt], 0,0,0);
                acc[mt][nt] = __builtin_amdgcn_mfma_f32_16x16x32_bf16(al[mt], bh, acc[mt][nt], 0,0,0);
                acc[mt][nt] = __builtin_amdgcn_mfma_f32_16x16x32_bf16(ah[mt], bl, acc[mt][nt], 0,0,0);
            }
        }
        __syncthreads();
    }

#pragma unroll
    for (int nt=0;nt<5;nt++){
        int col = n0 + wn*80 + nt*16 + ln;
        float bv = bias[col];
#pragma unroll
        for (int mt=0;mt<4;mt++){
#pragma unroll
            for (int r=0;r<4;r++){
                long row = m0 + wm*64 + mt*16 + g*4 + r;
                float x = acc[mt][nt][r] + bv;
                x = x > 0.f ? x : expm1f(x);
                C[row*N + col] = x;
            }
        }
    }
}

// ============================ bf16 GEMM (A bf16, W single-plane) ============
__global__ __launch_bounds__(NTH)
void gemm_bf(const ushort* __restrict__ A0, const ushort* __restrict__ A1,
             const ushort* __restrict__ Wh0, const ushort* __restrict__ Wh1,
             const float* __restrict__ b0, const float* __restrict__ b1,
             ushort* __restrict__ C0, ushort* __restrict__ C1, int N)
{
    const int z = blockIdx.z;
    const ushort* A  = z ? A1 : A0;
    const ushort* Wh = z ? Wh1 : Wh0;
    const float* bias = z ? b1 : b0;
    ushort* C = z ? C1 : C0;

    __shared__ ushort sA[128*40];
    __shared__ ushort sW[160*40];

    const int tid = threadIdx.x;
    const int lane = tid & 63, wave = tid >> 6;
    const int wm = wave >> 1, wn = wave & 1;
    const int ln = lane & 15, g = lane >> 4;
    const long m0 = (long)blockIdx.x * 128;
    const int  n0 = blockIdx.y * 160;

    f32x4 acc[4][5];
#pragma unroll
    for (int mt=0;mt<4;mt++)
#pragma unroll
        for (int nt=0;nt<5;nt++)
#pragma unroll
            for (int r=0;r<4;r++) acc[mt][nt][r] = 0.f;

    for (int k0=0;k0<160;k0+=32){
#pragma unroll
        for (int i=0;i<2;i++){
            int e = tid + 256*i;
            int m = e >> 2, seg = e & 3;
            *(uint4*)(sA + m*40 + seg*8) =
                *(const uint4*)(A + (m0+m)*160 + k0 + seg*8);
        }
#pragma unroll
        for (int i=0;i<3;i++){
            int e = tid + 256*i;
            if (e < 640){
                int n = e >> 2, seg = e & 3;
                *(uint4*)(sW + n*40 + seg*8) =
                    *(const uint4*)(Wh + (long)(n0+n)*160 + k0 + seg*8);
            }
        }
        __syncthreads();

        bf16x8 af[4];
#pragma unroll
        for (int mt=0;mt<4;mt++)
            af[mt] = *(const bf16x8*)(sA + (wm*64 + mt*16 + ln)*40 + g*8);
#pragma unroll
        for (int nt=0;nt<5;nt++){
            bf16x8 bh = *(const bf16x8*)(sW + (wn*80 + nt*16 + ln)*40 + g*8);
#pragma unroll
            for (int mt=0;mt<4;mt++)
                acc[mt][nt] = __builtin_amdgcn_mfma_f32_16x16x32_bf16(af[mt], bh, acc[mt][nt], 0,0,0);
        }
        __syncthreads();
    }

#pragma unroll
    for (int nt=0;nt<5;nt++){
        int col = n0 + wn*80 + nt*16 + ln;
        float bv = bias[col];
#pragma unroll
        for (int mt=0;mt<4;mt++){
#pragma unroll
            for (int r=0;r<4;r++){
                long row = m0 + wm*64 + mt*16 + g*4 + r;
                C[row*N + col] = f2bf(acc[mt][nt][r] + bv);
            }
        }
    }
}

// ============================ MFMA attention, layers 1/2 ============
__global__ __launch_bounds__(64)
void attn_layer_mfma(const ushort* __restrict__ XPi, const ushort* __restrict__ XPo,
                     const int* __restrict__ in_idx, const int* __restrict__ out_idx,
                     ushort* __restrict__ Oi, ushort* __restrict__ Oo, int node_base)
{
    const ushort* XP = blockIdx.y ? XPo : XPi;
    const int*  idx  = blockIdx.y ? out_idx : in_idx;
    ushort* O        = blockIdx.y ? Oo : Oi;

    __shared__ ushort XPg[16*496];
    __shared__ ushort Pall[5*16*24];

    const int lane = threadIdx.x;
    const int ln = lane & 15, q = lane >> 4;
    const int node = node_base + blockIdx.x;
    const int bb = node >> 12, nn = node & 4095;

    int idxv = nn;
    if (lane >= 1 && lane < 16) idxv = idx[(long)node*15 + lane-1];

#pragma unroll
    for (int i=0;i<15;i++){
        int e = lane + 64*i;
        int r = e/60, c = e - r*60;
        int rowg = __shfl(idxv, r);
        *(uint4*)(XPg + r*496 + c*8) =
            *(const uint4*)(XP + (long)(bb*4096 + rowg)*480 + c*8);
    }
    __syncthreads();

    const float scale = 0.17677669529663687f;
#pragma unroll
    for (int h=0;h<5;h++){
        bf16x8 ka = *(const bf16x8*)(XPg + ln*496 + 160 + h*32 + q*8);
        bf16x8 qb = *(const bf16x8*)(XPg + ln*496 +       h*32 + q*8);
        f32x4 s = {0.f,0.f,0.f,0.f};
        s = __builtin_amdgcn_mfma_f32_16x16x32_bf16(ka, qb, s, 0,0,0);
        float x[4], m = -1e30f;
#pragma unroll
        for (int r=0;r<4;r++){ x[r] = s[r]*scale; m = fmaxf(m, x[r]); }
        m = fmaxf(m, __shfl_xor(m, 16));
        m = fmaxf(m, __shfl_xor(m, 32));
        float e0[4], sum = 0.f;
#pragma unroll
        for (int r=0;r<4;r++){ e0[r] = __expf(x[r]-m); sum += e0[r]; }
        sum += __shfl_xor(sum, 16);
        sum += __shfl_xor(sum, 32);
        float inv = 1.f/sum;
        ushort4 pw;
        pw.x = f2bf(e0[0]*inv); pw.y = f2bf(e0[1]*inv);
        pw.z = f2bf(e0[2]*inv); pw.w = f2bf(e0[3]*inv);
        *(ushort4*)(Pall + h*384 + ln*24 + q*4) = pw;
    }
    __syncthreads();

#pragma unroll
    for (int h=0;h<5;h++){
        u16x8 ta;
#pragma unroll
        for (int jj=0;jj<8;jj++) ta[jj] = 0;
        if (q < 2) ta = *(const u16x8*)(Pall + h*384 + ln*24 + q*8);
        bf16x8 ap = *(bf16x8*)&ta;
#pragma unroll
        for (int half=0; half<2; half++){
            u16x8 tb;
#pragma unroll
            for (int jj=0;jj<8;jj++) tb[jj] = 0;
            if (q < 2){
#pragma unroll
                for (int jj=0;jj<8;jj++)
                    tb[jj] = XPg[(q*8+jj)*496 + 320 + h*32 + half*16 + ln];
            }
            bf16x8 bv = *(bf16x8*)&tb;
            f32x4 o = {0.f,0.f,0.f,0.f};
            o = __builtin_amdgcn_mfma_f32_16x16x32_bf16(ap, bv, o, 0,0,0);
#pragma unroll
            for (int r=0;r<4;r++)
                O[(long)(blockIdx.x*16 + q*4 + r)*160 + h*32 + half*16 + ln] = f2bf(o[r]);
        }
    }
}

// ============================ MFMA final attention + fused max-pool ============
__global__ __launch_bounds__(64)
void attn_final_pool(const ushort* __restrict__ FQi, const ushort* __restrict__ FQo,
                     const float* __restrict__ fb, float* __restrict__ pooled,
                     int node_base)
{
    __shared__ ushort F[32*328];
    __shared__ ushort P[32*40];

    const int lane = threadIdx.x;
    const int ln = lane & 15, q = lane >> 4;
    const int nl = blockIdx.x;

#pragma unroll
    for (int i=0;i<20;i++){
        int e = lane + 64*i;
        int r = e/40, c = e - r*40;
        const ushort* src = (r<16) ? (FQi + (long)(nl*16+r)*480 + c*8)
                                   : (FQo + (long)(nl*16+r-16)*480 + c*8);
        *(uint4*)(F + r*328 + c*8) = *(const uint4*)src;
    }
    __syncthreads();

    f32x4 sc[2][2];
#pragma unroll
    for (int ti=0;ti<2;ti++)
#pragma unroll
        for (int tj=0;tj<2;tj++){
            f32x4 a = {0.f,0.f,0.f,0.f};
#pragma unroll
            for (int kc=0;kc<5;kc++){
                bf16x8 ka = *(const bf16x8*)(F + (tj*16+ln)*328 + 160 + kc*32 + q*8);
                bf16x8 qb = *(const bf16x8*)(F + (ti*16+ln)*328 +       kc*32 + q*8);
                a = __builtin_amdgcn_mfma_f32_16x16x32_bf16(ka, qb, a, 0,0,0);
            }
            sc[ti][tj] = a;
        }

    const float scale = 0.07905694150420949f;
#pragma unroll
    for (int ti=0;ti<2;ti++){
        float x[2][4], m = -1e30f;
#pragma unroll
        for (int tj=0;tj<2;tj++)
#pragma unroll
            for (int r=0;r<4;r++){ x[tj][r] = sc[ti][tj][r]*scale; m = fmaxf(m, x[tj][r]); }
        m = fmaxf(m, __shfl_xor(m, 16));
        m = fmaxf(m, __shfl_xor(m, 32));
        float sum = 0.f;
#pragma unroll
        for (int tj=0;tj<2;tj++)
#pragma unroll
            for (int r=0;r<4;r++){ x[tj][r] = __expf(x[tj][r]-m); sum += x[tj][r]; }
        sum += __shfl_xor(sum, 16);
        sum += __shfl_xor(sum, 32);
        float inv = 1.f/sum;
#pragma unroll
        for (int tj=0;tj<2;tj++){
            ushort4 pw;
            pw.x = f2bf(x[tj][0]*inv); pw.y = f2bf(x[tj][1]*inv);
            pw.z = f2bf(x[tj][2]*inv); pw.w = f2bf(x[tj][3]*inv);
            *(ushort4*)(P + (ti*16+ln)*40 + tj*16 + q*4) = pw;
        }
    }
    __syncthreads();

#pragma unroll
    for (int i=0;i<10;i++){
        int e = lane + 64*i;
        int r = e/20, c = e - r*20;
        const ushort* src = (r<16) ? (FQi + (long)(nl*16+r)*480 + 320 + c*8)
                                   : (FQo + (long)(nl*16+r-16)*480 + 320 + c*8);
        *(uint4*)(F + r*168 + c*8) = *(const uint4*)src;
    }
    __syncthreads();

    bf16x8 ap[2];
#pragma unroll
    for (int mi=0;mi<2;mi++)
        ap[mi] = *(const bf16x8*)(P + (mi*16+ln)*40 + q*8);

    const int node = node_base + nl;
#pragma unroll
    for (int nt=0;nt<10;nt++){
        u16x8 tb;
#pragma unroll
        for (int jj=0;jj<8;jj++) tb[jj] = F[(q*8+jj)*168 + nt*16 + ln];
        bf16x8 bv = *(bf16x8*)&tb;
        float vmax = -1e30f;
#pragma unroll
        for (int mi=0;mi<2;mi++){
            f32x4 o = {0.f,0.f,0.f,0.f};
            o = __builtin_amdgcn_mfma_f32_16x16x32_bf16(ap[mi], bv, o, 0,0,0);
#pragma unroll
            for (int r=0;r<4;r++) vmax = fmaxf(vmax, o[r]);
        }
        vmax = fmaxf(vmax, __shfl_xor(vmax, 16));
        vmax = fmaxf(vmax, __shfl_xor(vmax, 32));
        if (q == 0){
            int col = nt*16 + ln;
            pooled[(long)node*160 + col] = vmax + fb[col];
        }
    }
}

// ============================ host ============================
extern "C" void kernel_launch(void* const* d_in, const int* in_sizes, int n_in,
                              void* d_out, int out_size, void* d_ws, size_t ws_size,
                              hipStream_t stream)
{
    const float* X       = (const float*)d_in[0];
    const int*   in_idx  = (const int*)  d_in[1];
    const int*   out_idx = (const int*)  d_in[2];
    const float* iWq     = (const float*)d_in[3];
    const float* iWk     = (const float*)d_in[4];
    const float* iWv     = (const float*)d_in[5];
    const float* i_in_w  = (const float*)d_in[6];
    const float* i_in_b  = (const float*)d_in[7];
    const float* i_out_w = (const float*)d_in[8];
    const float* i_out_b = (const float*)d_in[9];
    const float* oWq     = (const float*)d_in[10];
    const float* oWk     = (const float*)d_in[11];
    const float* oWv     = (const float*)d_in[12];
    const float* o_in_w  = (const float*)d_in[13];
    const float* o_in_b  = (const float*)d_in[14];
    const float* o_out_w = (const float*)d_in[15];
    const float* o_out_b = (const float*)d_in[16];
    const float* f_in_w  = (const float*)d_in[17];
    const float* f_in_b  = (const float*)d_in[18];
    const float* f_out_w = (const float*)d_in[19];
    const float* f_out_b = (const float*)d_in[20];
    const float* lin_w   = (const float*)d_in[21];
    const float* lin_b   = (const float*)d_in[22];

    float* ws = (float*)d_ws;
    float* pooled = ws;                           // 32768*160 fp32
    float* c_i    = pooled + 5242880;             // 480 (folded)
    float* c_o    = c_i + 480;
    float* cvt_i  = c_o + 480;                    // 480 raw
    float* cvt_o  = cvt_i + 480;
    float* Hvt_i  = cvt_o + 480;                  // 160x160 fp32
    float* Hvt_o  = Hvt_i + 25600;
    ushort* ub    = (ushort*)(Hvt_o + 25600);
    ushort* Xb    = ub;                           // 32768*160 bf16
    ushort* XPb_i = Xb + 5242880;                 // 32768*480 bf16
    ushort* XPb_o = XPb_i + 15728640;
    ushort* Wci_h = XPb_o + 15728640;             // 76800 each
    ushort* Wco_h = Wci_h + 76800;
    ushort* Hi_h  = Wco_h + 76800;
    ushort* Ho_h  = Hi_h  + 76800;
    ushort* li_h  = Ho_h  + 76800;                // 25600 each
    ushort* li_l  = li_h  + 25600;
    ushort* sb_us = li_l + 25600;
    const unsigned long long fixed = 23825280ULL;

    size_t avail = ws_size / 4;
    // ns=4096: slice working set (O 42MB + FQ 126MB + XP/batch ~8MB) < 256MB L3
    int ns = 4096;
    while (ns > 64 && fixed + 10240ULL*ns > avail) ns >>= 1;

    ushort* O_i = sb_us;                          // ns*16*160
    ushort* O_o = O_i + (size_t)2560*ns;
    ushort* FQi = O_o + (size_t)2560*ns;          // ns*16*480
    ushort* FQo = FQi + (size_t)7680*ns;

    prep_combined_bf<<<300,NTH,0,stream>>>(iWq,iWk,iWv,i_in_w, Wci_h);
    prep_combined_bf<<<300,NTH,0,stream>>>(oWq,oWk,oWv,o_in_w, Wco_h);
    prep_H_split<<<300,NTH,0,stream>>>(f_in_w, i_out_w, Hi_h, Hvt_i);
    prep_H_split<<<300,NTH,0,stream>>>(f_in_w, o_out_w, Ho_h, Hvt_o);
    prep_H_fold<<<100,NTH,0,stream>>>(f_out_w, Hvt_i, Hi_h);
    prep_H_fold<<<100,NTH,0,stream>>>(f_out_w, Hvt_o, Ho_h);
    prep_cvec<<<2,NTH,0,stream>>>(f_in_w, i_out_b, f_in_b, cvt_i);
    prep_cvec<<<2,NTH,0,stream>>>(f_in_w, o_out_b, f_in_b, cvt_o);
    prep_cvec_fold<<<2,NTH,0,stream>>>(f_out_w, cvt_i, c_i);
    prep_cvec_fold<<<2,NTH,0,stream>>>(f_out_w, cvt_o, c_o);
    prep_conv_bf2<<<100,NTH,0,stream>>>(lin_w, li_h, li_l, 25600);
    prep_conv_bf1<<<20480,NTH,0,stream>>>(X, Xb, 5242880);

    // XP = Xb @ Wc^T + in_b  -> bf16 (both layers via z)
    dim3 g1(256, 3, 2);
    gemm_bf<<<g1,NTH,0,stream>>>(Xb, Xb, Wci_h, Wco_h, i_in_b, o_in_b,
                                 XPb_i, XPb_o, 480);

    int S = 32768 / ns;
    for (int s=0;s<S;s++){
        int base = s*ns;
        dim3 ga(ns, 2);
        attn_layer_mfma<<<ga,64,0,stream>>>(XPb_i, XPb_o, in_idx, out_idx, O_i, O_o, base);
        dim3 g3(ns/8, 3, 2);
        gemm_bf<<<g3,NTH,0,stream>>>(O_i, O_o, Hi_h, Ho_h, c_i, c_o, FQi, FQo, 480);
        attn_final_pool<<<ns,64,0,stream>>>(FQi, FQo, f_out_b, pooled, base);
    }

    // out = ELU(pooled @ lin_w^T + lin_b)  fp32, split-x3
    dim3 g6(256, 1);
    gemm_mfma_lin<<<g6,NTH,0,stream>>>(pooled, li_h, li_l, lin_b, (float*)d_out, 160);
}